// Round 15
// baseline (58.971 us; speedup 1.0000x reference)
//
#include <hip/hip_runtime.h>

// AdaPT_Linear: per-tensor int8 quantized linear.
// out = (qx @ qw^T).f32 / (sa*sw) + qb.f32/sb
// x: [16384,1024] f32, w: [1024,1024] f32, b: [1024] f32, out: [16384,1024] f32

#define M_ROWS 16384
#define K_DIM  1024
#define N_OUT  1024

typedef int v4i __attribute__((ext_vector_type(4)));
typedef float v4f __attribute__((ext_vector_type(4)));

__device__ __forceinline__ void gload_lds16(const void* g, void* l) {
  __builtin_amdgcn_global_load_lds(
      (const __attribute__((address_space(1))) void*)g,
      (__attribute__((address_space(3))) void*)l, 16, 0, 0);
}

__device__ __forceinline__ float block_reduce_max4(float m, float* red) {
#pragma unroll
  for (int off = 32; off > 0; off >>= 1)
    m = fmaxf(m, __shfl_down(m, off));
  const int wid = threadIdx.x >> 6, lane = threadIdx.x & 63;
  if (lane == 0) red[wid] = m;
  __syncthreads();
  float r = fmaxf(fmaxf(red[0], red[1]), fmaxf(red[2], red[3]));
  __syncthreads();
  return r;
}

// fused: blocks [0,2048) reduce x -> px, blocks [2048,2304) reduce w -> pw
__global__ void amax_both(const float* __restrict__ x, const float* __restrict__ wsrc,
                          float* __restrict__ px, float* __restrict__ pw) {
  __shared__ float red[4];
  const bool isx = blockIdx.x < 2048;
  const float* src = isx ? x : wsrc;
  const int n4   = isx ? (M_ROWS * K_DIM / 4) : (N_OUT * K_DIM / 4);
  const int nblk = isx ? 2048 : 256;
  const int bidl = isx ? blockIdx.x : blockIdx.x - 2048;
  float m = 0.0f;
  const int stride = nblk * 256;
  for (int idx = bidl * 256 + threadIdx.x; idx < n4; idx += stride) {
    float4 v = ((const float4*)src)[idx];
    m = fmaxf(m, fmaxf(fmaxf(fabsf(v.x), fabsf(v.y)), fmaxf(fabsf(v.z), fabsf(v.w))));
  }
  float r = block_reduce_max4(m, red);
  if (threadIdx.x == 0) (isx ? px : pw)[bidl] = r;
}

__global__ void finalize_kernel(const float* __restrict__ px, int npx,
                                const float* __restrict__ pw, int npw,
                                const float* __restrict__ bias,
                                float* __restrict__ amax,
                                float* __restrict__ bdeq) {
  __shared__ float red[4];
  const int tid = threadIdx.x;

  float m = 0.0f;
  for (int i = tid; i < npx; i += 256) m = fmaxf(m, px[i]);
  float rx = block_reduce_max4(m, red);

  m = 0.0f;
  for (int i = tid; i < npw; i += 256) m = fmaxf(m, pw[i]);
  float rw = block_reduce_max4(m, red);

  float4 bv = ((const float4*)bias)[tid];  // 256*4 == 1024 exactly
  m = fmaxf(fmaxf(fabsf(bv.x), fabsf(bv.y)), fmaxf(fabsf(bv.z), fabsf(bv.w)));
  float rb = block_reduce_max4(m, red);

  if (rx == 0.0f) rx = 1.0f;
  if (rw == 0.0f) rw = 1.0f;
  if (rb == 0.0f) rb = 1.0f;
  if (tid == 0) {
    amax[0] = rx;
    amax[1] = rw;
    amax[2] = rb;
  }
  const float sb = 127.0f / rb;
  float4 q;
  q.x = fminf(fmaxf(rintf(sb * bv.x), -127.0f), 127.0f) / sb;
  q.y = fminf(fmaxf(rintf(sb * bv.y), -127.0f), 127.0f) / sb;
  q.z = fminf(fmaxf(rintf(sb * bv.z), -127.0f), 127.0f) / sb;
  q.w = fminf(fmaxf(rintf(sb * bv.w), -127.0f), 127.0f) / sb;
  ((float4*)bdeq)[tid] = q;
}

// fused: blocks [0,2048) quantize x -> qx, [2048,2304) w -> qw
__global__ void quant_both(const float* __restrict__ x, const float* __restrict__ wsrc,
                           signed char* __restrict__ qx, signed char* __restrict__ qw,
                           const float* __restrict__ amax) {
  const bool isx = blockIdx.x < 2048;
  const float* src = isx ? x : wsrc;
  signed char* dst = isx ? qx : qw;
  const int n4   = isx ? (M_ROWS * K_DIM / 4) : (N_OUT * K_DIM / 4);
  const int nblk = isx ? 2048 : 256;
  const int bidl = isx ? blockIdx.x : blockIdx.x - 2048;
  const float s = 127.0f / amax[isx ? 0 : 1];
  const int stride = nblk * 256;
  for (int idx = bidl * 256 + threadIdx.x; idx < n4; idx += stride) {
    float4 v = ((const float4*)src)[idx];
    int q0 = (int)fminf(fmaxf(rintf(s * v.x), -127.0f), 127.0f);
    int q1 = (int)fminf(fmaxf(rintf(s * v.y), -127.0f), 127.0f);
    int q2 = (int)fminf(fmaxf(rintf(s * v.z), -127.0f), 127.0f);
    int q3 = (int)fminf(fmaxf(rintf(s * v.w), -127.0f), 127.0f);
    unsigned int packed = (q0 & 0xff) | ((q1 & 0xff) << 8) |
                          ((q2 & 0xff) << 16) | ((q3 & 0xff) << 24);
    ((unsigned int*)dst)[idx] = packed;
  }
}

// ---------------------------------------------------------------------------
// i8 GEMM, 128x128 tile, BK=64, EIGHT waves (2Mx4N, wave=64x32), 512 thr,
// triple-buffered LDS 3x16KB = 48KB -> 2 blocks/CU -> 16 waves/CU =
// 4 waves/SIMD (was 2 in ALL prior rounds — the one untouched knob; R12
// ablation: MFMA core alone 56% util, full kernel 15% -> VM/BAR stalls need
// co-resident waves to hide under, and 2/SIMD gives only one alternate).
// R14-proven single-barrier order per kt:
//   {STG(tile kt+1 -> pS, 2 loads/thread); VM(2); BAR; 6 ds_read; 8 MFMA}
// vmcnt wave-local: VM(2) (2 just-issued remain) drains this wave's tile-kt
// loads; BAR publishes all waves' slices. 3-buf WAR: stage at kt targets
// buffer last read at kt-2 (reads drained pre-MFMA(kt-2), before BAR(kt-1);
// stager writes after its BAR(kt-1)). Tail: VM(0). Prologue: STG(buf0, t0).
// Swizzle: stored 16B-unit = gunit ^ ((row>>1)&3); row mod 8 == fr mod 8 so
// read-side XOR = (q ^ ((fr>>1)&3)); pre-swizzled global source (involution).
// Epilogue: per-wave 16x36-stride LDS transpose (16B-aligned rows) +
// nontemporal v4f stores (8 lanes x 16B = 128B contiguous per half-row).
// ---------------------------------------------------------------------------
#define NKT 16

__global__ __launch_bounds__(512, 4) void gemm_kernel(
    const signed char* __restrict__ qx, const signed char* __restrict__ qw,
    const float* __restrict__ amax, const float* __restrict__ bdeq,
    float* __restrict__ out) {
  __shared__ char lds[49152];  // 3 bufs x 16KB (A 8K + B 8K)

  const int tid  = threadIdx.x;
  const int w    = tid >> 6;
  const int lane = tid & 63;
  const int wm = w >> 2;   // 0..1 (64 rows)
  const int wn = w & 3;    // 0..3 (32 cols)
  const int fr = lane & 15;
  const int q  = lane >> 4;

  // XCD-aware swizzle (grid 1024 = 8 XCDs x 128 contiguous)
  const int bid = blockIdx.x;
  const int wg  = (bid & 7) * 128 + (bid >> 3);
  const int Mbase = (wg >> 3) * 128;
  const int Nbase = (wg & 7) * 128;

  const signed char* gA = qx + (size_t)Mbase * K_DIM;
  const signed char* gB = qw + (size_t)Nbase * K_DIM;

  // staging: thread t -> row t>>2 (0..127), source unit (t&3)^((t>>3)&3)
  const int scol = ((tid & 3) ^ ((tid >> 3) & 3)) << 4;
  const size_t srowK = (size_t)(tid >> 2) * K_DIM;
  // fragment read: row R -> stored unit q ^ ((R>>1)&3) = q ^ ((fr>>1)&3)
  const int u0 = (q ^ ((fr >> 1) & 3)) << 4;

  const float inv_denom = (amax[0] * amax[1]) * (1.0f / 16129.0f);

  v4i acc[4][2] = {};
  v4i Ar[4], Br[2];

#define STG(BASE, T)                                                           \
  do {                                                                         \
    const int _k0 = (T)*64 + scol;                                             \
    gload_lds16(gA + srowK + _k0, (BASE) + tid * 16);                          \
    gload_lds16(gB + srowK + _k0, (BASE) + 8192 + tid * 16);                   \
  } while (0)

#define VM(N) asm volatile("s_waitcnt vmcnt(" #N ")" ::: "memory")
#define LGKM0() asm volatile("s_waitcnt lgkmcnt(0)" ::: "memory")

  char* pR = lds;           // read buffer (tile kt)
  char* pS = lds + 16384;   // stage target (tile kt+1)
  char* pF = lds + 32768;   // staged next iter (read at kt+2)

  STG(pR, 0);  // prologue: tile 0

#pragma unroll
  for (int kt = 0; kt < NKT; ++kt) {
    if (kt + 1 < NKT) {
      STG(pS, kt + 1);
      VM(2);  // this wave's tile-kt loads landed (2 just-issued remain)
    } else {
      VM(0);
    }
    __builtin_amdgcn_s_barrier();  // publish all waves' slices of tile kt

    const char* _A = pR + wm * 4096;            // 64 rows x 64B
    const char* _B = pR + 8192 + wn * 2048;     // 32 rows x 64B
#pragma unroll
    for (int f = 0; f < 4; ++f)
      Ar[f] = *(const v4i*)(_A + f * 1024 + fr * 64 + u0);
#pragma unroll
    for (int g = 0; g < 2; ++g)
      Br[g] = *(const v4i*)(_B + g * 1024 + fr * 64 + u0);
#pragma unroll
    for (int f = 0; f < 4; ++f)
#pragma unroll
      for (int g = 0; g < 2; ++g)
        acc[f][g] = __builtin_amdgcn_mfma_i32_16x16x64_i8(Ar[f], Br[g], acc[f][g], 0, 0, 0);

    char* t = pR; pR = pS; pS = pF; pF = t;  // rotate
  }
#undef STG

  // ------------------------ epilogue (store-path) --------------------------
  __syncthreads();  // final tile reads drained; repurpose LDS

  float bdq[2];
#pragma unroll
  for (int g = 0; g < 2; ++g) bdq[g] = bdeq[Nbase + wn * 32 + g * 16 + fr];

  float* lws = (float*)(lds + w * 4096);  // 16 x 36 f32 = 2304B per wave

  const int erow = lane >> 3;   // 0..7
  const int ecg  = lane & 7;    // 8 x 16B = 128B per 8 lanes
  float* const orow_base = out + (size_t)(Mbase + wm * 64) * N_OUT +
                           (Nbase + wn * 32) + ecg * 4;

#pragma unroll
  for (int f = 0; f < 4; ++f) {
    // scatter scaled acc: [row16 = q*4+i][col = g*16+fr], stride 36 (aligned)
#pragma unroll
    for (int g = 0; g < 2; ++g)
#pragma unroll
      for (int i = 0; i < 4; ++i)
        lws[(q * 4 + i) * 36 + g * 16 + fr] =
            (float)acc[f][g][i] * inv_denom + bdq[g];
    LGKM0();  // wave-local ordering
#pragma unroll
    for (int t = 0; t < 2; ++t) {
      const int r16 = t * 8 + erow;
      v4f v = *(const v4f*)&lws[r16 * 36 + ecg * 4];
      __builtin_nontemporal_store(
          v, (v4f*)(orow_base + (size_t)(f * 16 + r16) * N_OUT));
    }
    LGKM0();  // reads done before overwrite
  }
#undef VM
#undef LGKM0
}

extern "C" void kernel_launch(void* const* d_in, const int* in_sizes, int n_in,
                              void* d_out, int out_size, void* d_ws, size_t ws_size,
                              hipStream_t stream) {
  const float* x = (const float*)d_in[0];
  const float* w = (const float*)d_in[1];
  const float* b = (const float*)d_in[2];
  float* out = (float*)d_out;

  char* ws = (char*)d_ws;
  float* amax = (float*)ws;                             // 3 floats
  float* bdeq = (float*)(ws + 256);                     // 4 KB
  float* px   = (float*)(ws + 8192);                    // 2048 partials
  float* pw   = (float*)(ws + 16384 + 8192);            // 256 partials
  signed char* qw = (signed char*)(ws + 65536);         // 1 MB
  signed char* qx = (signed char*)(ws + (1 << 21));     // 16 MB

  const int NPX = 2048, NPW = 256;
  hipLaunchKernelGGL(amax_both, dim3(NPX + NPW), dim3(256), 0, stream, x, w, px, pw);
  hipLaunchKernelGGL(finalize_kernel, dim3(1), dim3(256), 0, stream, px, NPX, pw, NPW, b, amax, bdeq);
  hipLaunchKernelGGL(quant_both, dim3(NPX + NPW), dim3(256), 0, stream, x, w, qx, qw, amax);
  hipLaunchKernelGGL(gemm_kernel, dim3(128 * 8), dim3(512), 0, stream, qx, qw, amax, bdeq, out);
}